// Round 16
// baseline (258.045 us; speedup 1.0000x reference)
//
#include <hip/hip_runtime.h>
#include <hip/hip_bf16.h>

#define M_TOK 2048
#define K_DIM 1024
#define E_NUM 8
#define DFF   2816
#define TOPK  2
#define NROWS (M_TOK*TOPK)   // 4096 routed rows
#define KSPLIT 4
#define DSLICE (DFF/KSPLIT)          // 704
#define KT2    (DSLICE/64)           // 11
#define KT1    (K_DIM/64)            // 16

typedef __bf16 bf16;
typedef __bf16 bf16x8 __attribute__((ext_vector_type(8)));
typedef __bf16 bf16x4 __attribute__((ext_vector_type(4)));
typedef float  f32x4  __attribute__((ext_vector_type(4)));

__device__ __forceinline__ void gload_lds16(const void* g, void* l) {
    __builtin_amdgcn_global_load_lds(
        (const __attribute__((address_space(1))) void*)g,
        (__attribute__((address_space(3))) void*)l, 16, 0, 0);
}

// ---------------------------------------------------------------------------
// Fused zero(d_out) + routing. Block 0 routes; blocks >=1 zero the output.
// ---------------------------------------------------------------------------
__global__ __launch_bounds__(512)
void route_zero_kernel(const int* __restrict__ ids,
                       const float* __restrict__ tw,
                       int* __restrict__ counts, int* __restrict__ offs,
                       int* __restrict__ row_token, float* __restrict__ row_wgt,
                       float* __restrict__ out, int n4)
{
    if (blockIdx.x != 0) {
        int i = (blockIdx.x - 1) * 512 + threadIdx.x;
        int stride = (gridDim.x - 1) * 512;
        f32x4 z = (f32x4){0.f, 0.f, 0.f, 0.f};
        for (; i < n4; i += stride) ((f32x4*)out)[i] = z;
        return;
    }
    const int e    = threadIdx.x >> 6;
    const int lane = threadIdx.x & 63;
    __shared__ int scnt[E_NUM];

    int cnt = 0;
    for (int i0 = 0; i0 < NROWS; i0 += 64) {
        int id = ids[i0 + lane];
        cnt += __popcll(__ballot(id == e));
    }
    if (lane == 0) scnt[e] = cnt;
    __syncthreads();
    int base = 0;
    for (int j = 0; j < e; ++j) base += scnt[j];
    if (lane == 0) { counts[e] = cnt; offs[e] = base; }

    const unsigned long long ltmask = (1ull << lane) - 1ull;
    int pos = base;
    for (int i0 = 0; i0 < NROWS; i0 += 64) {
        int i = i0 + lane;
        int id = ids[i];
        unsigned long long m = __ballot(id == e);
        if (id == e) {
            int rank = __popcll(m & ltmask);
            row_token[pos + rank] = i >> 1;
            row_wgt[pos + rank]   = tw[i];
        }
        pos += __popcll(m);
    }
}

// ---------------------------------------------------------------------------
// Gather routed rows of X and cast to bf16 (A operand; 8 MB, ~4us).
// ---------------------------------------------------------------------------
__global__ __launch_bounds__(256)
void gather_cast_kernel(const float* __restrict__ X, const int* __restrict__ row_token,
                        bf16* __restrict__ Ag)
{
    const int row = blockIdx.x;
    const int tok = row_token[row];
    f32x4 a = ((const f32x4*)(X + (size_t)tok * K_DIM))[threadIdx.x];
    bf16x4 v;
    #pragma unroll
    for (int j = 0; j < 4; ++j) v[j] = (bf16)a[j];
    ((bf16x4*)(Ag + (size_t)row * K_DIM))[threadIdx.x] = v;
}

// ---------------------------------------------------------------------------
// GEMM1 + silu_and_mul, 256-row tile, counted-wait pipeline:
//   top: vmcnt(0) waits ONLY the A/B prefetches issued one compute ago
//   BWRITE(kt): f32 regs -> cvt -> bf16 ds_write (B LDS bytes halved)
//   issue GLOADA(kt+1 -> A[cur^1]) + BLOAD(kt+1 -> regs): fly over COMPUTE(kt)
//   lgkmcnt(0); s_barrier; COMPUTE(cur); s_barrier     (no __syncthreads!)
// A: dbuf [2][256][64] bf16 (64KB), law chunk^(r&7). B: [128][64] bf16 (16KB),
// same law on write & read. LDS 80KB -> 2 blocks/CU.
// ---------------------------------------------------------------------------
__global__ __launch_bounds__(256, 2)
void gemm1_kernel(const bf16* __restrict__ Ag, const float* __restrict__ w1,
                  const int* __restrict__ counts, const int* __restrict__ offs,
                  bf16* __restrict__ act)
{
    const int e  = blockIdx.z;
    const int rt = blockIdx.y;
    const int ct = blockIdx.x;              // 0..43
    const int n  = counts[e];
    const int r0 = rt * 256;
    if (r0 >= n) return;
    const int base = offs[e];

    __shared__ __align__(16) bf16 As[2][256*64];   // 64 KB
    __shared__ __align__(16) bf16 Bs[128*64];      // 16 KB
    bf16x8* Asv = (bf16x8*)As;              // 2048 units / buffer
    bf16x8* Bsv = (bf16x8*)Bs;              // 1024 units

    const int t    = threadIdx.x;
    const int lane = t & 63, wv = t >> 6;

    // A staging (gload_lds): 8 loads/thread, rows wv*64+i*8+(lane>>3)
    const int rlowA = lane >> 3;
    const int cgA   = (lane & 7) ^ rlowA;
    const bf16* aPtr[8]; bf16* aLds[8];
    #pragma unroll
    for (int i = 0; i < 8; ++i) {
        int r = wv*64 + i*8 + rlowA;        // 0..255
        aPtr[i] = Ag + (size_t)(base + r0 + r) * K_DIM + cgA*8;
        aLds[i] = As[0] + (wv*64 + i*8)*64;
    }

    // B staging (reg): wave owns rows wv*32..+31; q=0..3 rows wv*32+q*8+(lane>>3);
    // 8 consecutive f32 at chunk (lane&7)*8. Write bf16 chunk (lane&7)^(row&7).
    const int rlowB = lane >> 3;
    const int cB    = lane & 7;
    const float* bRow[4]; int bLrow[4];
    #pragma unroll
    for (int q = 0; q < 4; ++q) {
        int r = wv*32 + q*8 + rlowB;        // 0..127 (gate 0-63, up 64-127)
        int w1row = (r < 64) ? (ct*64 + r) : (DFF + ct*64 + (r - 64));
        bRow[q] = w1 + ((size_t)e*(2*DFF) + w1row) * K_DIM + cB*8;
        bLrow[q] = r;
    }

    const int wr = wv >> 1, wc = wv & 1;
    const int l15 = lane & 15, lq = lane >> 4;

    f32x4 accG[8][2], accU[8][2];
    #pragma unroll
    for (int m = 0; m < 8; ++m)
        #pragma unroll
        for (int nn = 0; nn < 2; ++nn) {
            accG[m][nn] = (f32x4){0.f,0.f,0.f,0.f};
            accU[m][nn] = (f32x4){0.f,0.f,0.f,0.f};
        }

    f32x4 blo[4], bhi[4];

#define G1_GLOADA(KT_, B_) do { \
    _Pragma("unroll") for (int i = 0; i < 8; ++i) \
        gload_lds16(aPtr[i] + (KT_)*64, aLds[i] + (B_)*(256*64)); \
    } while (0)

#define G1_BLOAD(KT_) do { \
    _Pragma("unroll") for (int q = 0; q < 4; ++q) { \
        const f32x4* p_ = (const f32x4*)(bRow[q] + (KT_)*64); \
        blo[q] = p_[0]; bhi[q] = p_[1]; \
    } } while (0)

#define G1_BWRITE() do { \
    _Pragma("unroll") for (int q = 0; q < 4; ++q) { \
        bf16x8 v_; \
        _Pragma("unroll") for (int j = 0; j < 4; ++j) { v_[j]=(bf16)blo[q][j]; v_[j+4]=(bf16)bhi[q][j]; } \
        Bsv[bLrow[q]*8 + (cB ^ (bLrow[q] & 7))] = v_; \
    } } while (0)

#define G1_COMPUTE(CUR_) do { \
    _Pragma("unroll") for (int ks = 0; ks < 2; ++ks) { \
        bf16x8 bg[2], bu[2]; \
        _Pragma("unroll") for (int nn = 0; nn < 2; ++nn) { \
            int frg = wc*32 + nn*16 + l15; \
            bg[nn] = Bsv[frg*8 + ((ks*4 + lq) ^ (frg & 7))]; \
            int fru = 64 + wc*32 + nn*16 + l15; \
            bu[nn] = Bsv[fru*8 + ((ks*4 + lq) ^ (fru & 7))]; \
        } \
        _Pragma("unroll") for (int m = 0; m < 8; ++m) { \
            int fr = wr*128 + m*16 + l15; \
            bf16x8 af = Asv[(CUR_)*2048 + fr*8 + ((ks*4 + lq) ^ (fr & 7))]; \
            _Pragma("unroll") for (int nn = 0; nn < 2; ++nn) { \
                accG[m][nn] = __builtin_amdgcn_mfma_f32_16x16x32_bf16(af, bg[nn], accG[m][nn], 0, 0, 0); \
                accU[m][nn] = __builtin_amdgcn_mfma_f32_16x16x32_bf16(af, bu[nn], accU[m][nn], 0, 0, 0); \
            } \
        } \
    } } while (0)

    G1_BLOAD(0);
    G1_GLOADA(0, 0);
    for (int kt = 0; kt < KT1; ++kt) {
        const int cur = kt & 1;
        asm volatile("s_waitcnt vmcnt(0)" ::: "memory");   // A(kt) in LDS, B(kt) in regs
        G1_BWRITE();                                        // Bbuf <- bf16(B kt)
        if (kt + 1 < KT1) {
            G1_GLOADA(kt + 1, cur ^ 1);                     // flies over compute
            G1_BLOAD(kt + 1);                               // flies over compute
        }
        asm volatile("s_waitcnt lgkmcnt(0)" ::: "memory");  // ds_writes visible
        __builtin_amdgcn_s_barrier();
        G1_COMPUTE(cur);
        __builtin_amdgcn_s_barrier();
    }

    // epilogue: act = silu(gate) * up  (C/D: col=lane&15, row=(lane>>4)*4+r)
    #pragma unroll
    for (int m = 0; m < 8; ++m)
        #pragma unroll
        for (int nn = 0; nn < 2; ++nn)
            #pragma unroll
            for (int r = 0; r < 4; ++r) {
                int rl = wr*128 + m*16 + lq*4 + r;
                int grow = r0 + rl;
                if (grow < n) {
                    float g = accG[m][nn][r];
                    float u = accU[m][nn][r];
                    float a = (g / (1.f + __expf(-g))) * u;
                    int col = ct*64 + wc*32 + nn*16 + l15;
                    act[(size_t)(base + grow) * DFF + col] = (bf16)a;
                }
            }
#undef G1_GLOADA
#undef G1_BLOAD
#undef G1_BWRITE
#undef G1_COMPUTE
}

// ---------------------------------------------------------------------------
// GEMM2: 128-row tile, KSPLIT=4, same counted-wait pipeline; B = w2 f32->bf16
// reg-staged. LDS 48KB -> 3 blocks/CU. Atomic scatter epilogue.
// ---------------------------------------------------------------------------
__global__ __launch_bounds__(256, 2)
void gemm2_kernel(const bf16* __restrict__ act, const float* __restrict__ w2,
                  const int* __restrict__ counts, const int* __restrict__ offs,
                  const int* __restrict__ row_token, const float* __restrict__ row_wgt,
                  float* __restrict__ out)
{
    const int e   = blockIdx.z;
    const int rt  = blockIdx.y;
    const int ct  = blockIdx.x >> 2;          // 0..7 : 128 out cols
    const int ksp = blockIdx.x & 3;           // DFF quarter
    const int n   = counts[e];
    const int r0  = rt * 128;
    if (r0 >= n) return;
    const int base = offs[e];

    __shared__ __align__(16) bf16 As[2][128*64];   // 32 KB
    __shared__ __align__(16) bf16 Bs[128*64];      // 16 KB
    bf16x8* Asv = (bf16x8*)As;              // 1024 units / buffer
    bf16x8* Bsv = (bf16x8*)Bs;

    const int t    = threadIdx.x;
    const int lane = t & 63, wv = t >> 6;

    const int rlowA = lane >> 3;
    const int cgA   = (lane & 7) ^ rlowA;
    const bf16* aPtr[4]; bf16* aLds[4];
    #pragma unroll
    for (int i = 0; i < 4; ++i) {
        int r = wv*32 + i*8 + rlowA;
        aPtr[i] = act + (size_t)(base + r0 + r) * DFF + ksp*DSLICE + cgA*8;
        aLds[i] = As[0] + (wv*32 + i*8)*64;
    }

    const int rlowB = lane >> 3;
    const int cB    = lane & 7;
    const float* bRow[4]; int bLrow[4];
    #pragma unroll
    for (int q = 0; q < 4; ++q) {
        int r = wv*32 + q*8 + rlowB;        // out-col row 0..127
        bRow[q] = w2 + ((size_t)e*K_DIM + ct*128 + r) * DFF + ksp*DSLICE + cB*8;
        bLrow[q] = r;
    }

    const int wr = wv >> 1, wc = wv & 1;
    const int l15 = lane & 15, lq = lane >> 4;

    f32x4 acc[4][4];
    #pragma unroll
    for (int m = 0; m < 4; ++m)
        #pragma unroll
        for (int nn = 0; nn < 4; ++nn) acc[m][nn] = (f32x4){0.f,0.f,0.f,0.f};

    f32x4 blo[4], bhi[4];

#define G2_GLOADA(KT_, B_) do { \
    _Pragma("unroll") for (int i = 0; i < 4; ++i) \
        gload_lds16(aPtr[i] + (KT_)*64, aLds[i] + (B_)*(128*64)); \
    } while (0)

#define G2_BLOAD(KT_) do { \
    _Pragma("unroll") for (int q = 0; q < 4; ++q) { \
        const f32x4* p_ = (const f32x4*)(bRow[q] + (KT_)*64); \
        blo[q] = p_[0]; bhi[q] = p_[1]; \
    } } while (0)

#define G2_BWRITE() do { \
    _Pragma("unroll") for (int q = 0; q < 4; ++q) { \
        bf16x8 v_; \
        _Pragma("unroll") for (int j = 0; j < 4; ++j) { v_[j]=(bf16)blo[q][j]; v_[j+4]=(bf16)bhi[q][j]; } \
        Bsv[bLrow[q]*8 + (cB ^ (bLrow[q] & 7))] = v_; \
    } } while (0)

#define G2_COMPUTE(CUR_) do { \
    _Pragma("unroll") for (int ks = 0; ks < 2; ++ks) { \
        bf16x8 af[4], bf[4]; \
        _Pragma("unroll") for (int m = 0; m < 4; ++m) { \
            int fr = wr*64 + m*16 + l15; \
            af[m] = Asv[(CUR_)*1024 + fr*8 + ((ks*4 + lq) ^ (fr & 7))]; \
        } \
        _Pragma("unroll") for (int nn = 0; nn < 4; ++nn) { \
            int fr = wc*64 + nn*16 + l15; \
            bf[nn] = Bsv[fr*8 + ((ks*4 + lq) ^ (fr & 7))]; \
        } \
        _Pragma("unroll") for (int m = 0; m < 4; ++m) \
            _Pragma("unroll") for (int nn = 0; nn < 4; ++nn) \
                acc[m][nn] = __builtin_amdgcn_mfma_f32_16x16x32_bf16(af[m], bf[nn], acc[m][nn], 0, 0, 0); \
    } } while (0)

    G2_BLOAD(0);
    G2_GLOADA(0, 0);
    for (int kt = 0; kt < KT2; ++kt) {
        const int cur = kt & 1;
        asm volatile("s_waitcnt vmcnt(0)" ::: "memory");
        G2_BWRITE();
        if (kt + 1 < KT2) {
            G2_GLOADA(kt + 1, cur ^ 1);
            G2_BLOAD(kt + 1);
        }
        asm volatile("s_waitcnt lgkmcnt(0)" ::: "memory");
        __builtin_amdgcn_s_barrier();
        G2_COMPUTE(cur);
        __builtin_amdgcn_s_barrier();
    }

    #pragma unroll
    for (int m = 0; m < 4; ++m)
        #pragma unroll
        for (int nn = 0; nn < 4; ++nn)
            #pragma unroll
            for (int r = 0; r < 4; ++r) {
                int rl = wr*64 + m*16 + lq*4 + r;
                int grow = r0 + rl;
                if (grow < n) {
                    int idx = base + grow;
                    int tok   = row_token[idx];
                    float wgt = row_wgt[idx];
                    int col = ct*128 + wc*64 + nn*16 + l15;
                    atomicAdd(out + (size_t)tok * K_DIM + col, wgt * acc[m][nn][r]);
                }
            }
#undef G2_GLOADA
#undef G2_BLOAD
#undef G2_BWRITE
#undef G2_COMPUTE
}

// ---------------------------------------------------------------------------
extern "C" void kernel_launch(void* const* d_in, const int* in_sizes, int n_in,
                              void* d_out, int out_size, void* d_ws, size_t ws_size,
                              hipStream_t stream)
{
    const float* X   = (const float*)d_in[0];
    const float* w1  = (const float*)d_in[1];
    const float* w2  = (const float*)d_in[2];
    const float* tw  = (const float*)d_in[3];
    const int*   ids = (const int*)d_in[4];
    float* out = (float*)d_out;

    // ws layout: act | row_token | row_wgt | counts | offs | Ag | pad
    char* p = (char*)d_ws;
    bf16*  act       = (bf16*)p;   p += (size_t)NROWS * DFF * 2;
    int*   row_token = (int*)p;    p += (size_t)NROWS * 4;
    float* row_wgt   = (float*)p;  p += (size_t)NROWS * 4;
    int*   counts    = (int*)p;    p += 32;
    int*   offs      = (int*)p;    p += 32;
    bf16*  Ag        = (bf16*)p;   p += (size_t)NROWS * K_DIM * 2;
    p += (1u << 20);               // 1 MB pad for benign A-row overreads
    (void)p; (void)ws_size;        // ~33 MB needed; ws >= 162 MB verified r8-11

    route_zero_kernel<<<64, 512, 0, stream>>>(ids, tw, counts, offs, row_token,
                                              row_wgt, out, out_size / 4);
    gather_cast_kernel<<<NROWS, 256, 0, stream>>>(X, row_token, Ag);
    gemm1_kernel<<<dim3(DFF/64, NROWS/256, E_NUM), 256, 0, stream>>>(Ag, w1, counts, offs, act);
    gemm2_kernel<<<dim3((K_DIM/128)*KSPLIT, NROWS/128, E_NUM), 256, 0, stream>>>(act, w2, counts, offs, row_token, row_wgt, out);
}